// Round 4
// baseline (36.077 us; speedup 1.0000x reference)
//
#include <hip/hip_runtime.h>

typedef __bf16 bf16x8 __attribute__((ext_vector_type(8)));
typedef float f32x4 __attribute__((ext_vector_type(4)));

constexpr int NP   = 256;   // n_patches
constexpr int DM   = 1024;  // d_model
constexpr int PRED = 720;
constexpr int P0   = 233;   // first contributing patch
constexpr int NPC  = 23;    // patches 233..255
constexpr int TMIN = 7504;  // total_len - PRED
constexpr int KG   = 2;     // K-split across grid.z
constexpr int WK   = 128;   // K per wave (KG * 4 waves * 128 = 1024)

// GEMM: grid (23, 32, KG), block 256 = 4 waves.
// Wave w handles 16 batches x 64 j over K-window [kg*512 + w*128, +128).
// B (W) is loaded fp32 -> converted to bf16 fragments in registers ONCE.
// Block reduces its 4 wave-partials in LDS, stores one partial plane to ws.
__global__ __launch_bounds__(256) void ph_gemm(
    const float* __restrict__ x,   // [512][256][1024]
    const float* __restrict__ W,   // [64][1024]
    float* __restrict__ zp)        // [KG][512][NPC][64] partials
{
    const int pi   = blockIdx.x;
    const int p    = P0 + pi;
    const int kg   = blockIdx.z;
    const int lane = threadIdx.x & 63;
    const int wave = threadIdx.x >> 6;      // 0..3
    const int r16  = lane & 15;
    const int kgrp = lane >> 4;
    const int bbase = blockIdx.y * 16;
    const int kbase = kg * 512 + wave * WK;

    __shared__ float red[4][16][65];

    // ---- B prologue: W[n*16+r16][kbase + s*32 + kgrp*8 .. +8] -> bf16 regs ----
    bf16x8 bfrag[4][4];                      // [n][k0-step]
    {
        const float* wr = W + (size_t)r16 * DM + kbase + kgrp * 8;
        #pragma unroll
        for (int n = 0; n < 4; ++n)
            #pragma unroll
            for (int s = 0; s < 4; ++s) {
                const float4 b0 = *(const float4*)(wr + (size_t)n * 16 * DM + s * 32);
                const float4 b1 = *(const float4*)(wr + (size_t)n * 16 * DM + s * 32 + 4);
                bf16x8 bf;
                bf[0]=(__bf16)b0.x; bf[1]=(__bf16)b0.y; bf[2]=(__bf16)b0.z; bf[3]=(__bf16)b0.w;
                bf[4]=(__bf16)b1.x; bf[5]=(__bf16)b1.y; bf[6]=(__bf16)b1.z; bf[7]=(__bf16)b1.w;
                bfrag[n][s] = bf;
            }
    }

    // ---- main loop: stream A (x rows), 4 MFMA per 32-K step ----
    const float* xrow = x + ((size_t)(bbase + r16) * NP + p) * DM + kbase + kgrp * 8;

    f32x4 acc[4];
    #pragma unroll
    for (int n = 0; n < 4; ++n) acc[n] = (f32x4){0.f, 0.f, 0.f, 0.f};

    #pragma unroll
    for (int s = 0; s < 4; ++s) {
        const float4 a0 = *(const float4*)(xrow + s * 32);
        const float4 a1 = *(const float4*)(xrow + s * 32 + 4);
        bf16x8 af;
        af[0]=(__bf16)a0.x; af[1]=(__bf16)a0.y; af[2]=(__bf16)a0.z; af[3]=(__bf16)a0.w;
        af[4]=(__bf16)a1.x; af[5]=(__bf16)a1.y; af[6]=(__bf16)a1.z; af[7]=(__bf16)a1.w;
        #pragma unroll
        for (int n = 0; n < 4; ++n)
            acc[n] = __builtin_amdgcn_mfma_f32_16x16x32_bf16(af, bfrag[n][s], acc[n], 0, 0, 0);
    }

    // ---- reduce 4 waves in LDS ----
    // D layout (m89): col(j) = n*16 + (lane&15), row(batch) = (lane>>4)*4 + reg.
    #pragma unroll
    for (int n = 0; n < 4; ++n)
        #pragma unroll
        for (int r = 0; r < 4; ++r)
            red[wave][kgrp * 4 + r][n * 16 + r16] = acc[n][r];

    __syncthreads();

    // ---- store one [16][64] partial plane, float4 per thread ----
    const int r  = threadIdx.x >> 4;         // 0..15
    const int j0 = (threadIdx.x & 15) * 4;   // 0..60
    f32x4 v;
    #pragma unroll
    for (int q = 0; q < 4; ++q) {
        float s = 0.f;
        #pragma unroll
        for (int w = 0; w < 4; ++w) s += red[w][r][j0 + q];
        v[q] = s;
    }
    float* dst = zp + (((size_t)kg * 512 + bbase + r) * NPC + pi) * 64 + j0;
    *(f32x4*)dst = v;
}

// Fold: out[b][o] from <=2 contributing (p,j) + bias, / count. Writes ALL out.
__global__ __launch_bounds__(256) void ph_fold(
    const float* __restrict__ zp,    // [KG][512][NPC][64]
    const float* __restrict__ bias,  // [64]
    float* __restrict__ out)         // [512][720]
{
    const int i = blockIdx.x * 256 + threadIdx.x;   // 512*720 = 368640 = 1440*256
    const int b = i / PRED;
    const int o = i - b * PRED;
    const int t = o + TMIN;                  // 7504..8223
    const int ph = t >> 5;                   // 234..256
    const int j  = t & 31;
    const int pl = ph - 1;                   // 233..255 (always valid)
    const bool hi = (ph <= 255);

    const size_t plane = (size_t)512 * NPC * 64;
    const size_t base  = (size_t)b * NPC * 64;

    float a = zp[base + (size_t)(pl - P0) * 64 + (j + 32)]
            + zp[plane + base + (size_t)(pl - P0) * 64 + (j + 32)]
            + bias[j + 32];
    if (hi) {
        float h = zp[base + (size_t)(ph - P0) * 64 + j]
                + zp[plane + base + (size_t)(ph - P0) * 64 + j]
                + bias[j];
        a = (a + h) * 0.5f;
    }
    out[i] = a;
}

extern "C" void kernel_launch(void* const* d_in, const int* in_sizes, int n_in,
                              void* d_out, int out_size, void* d_ws, size_t ws_size,
                              hipStream_t stream) {
    const float* x    = (const float*)d_in[0];
    const float* W    = (const float*)d_in[1];
    const float* bias = (const float*)d_in[2];
    float* out = (float*)d_out;
    float* zp  = (float*)d_ws;   // [2][512][23][64] fp32 = 6.03 MB

    dim3 grid(NPC, 32, KG);
    ph_gemm<<<grid, dim3(256), 0, stream>>>(x, W, zp);
    ph_fold<<<dim3(512 * PRED / 256), dim3(256), 0, stream>>>(zp, bias, out);
}

// Round 5
// 31.799 us; speedup vs baseline: 1.1345x; 1.1345x over previous
//
#include <hip/hip_runtime.h>

typedef __bf16 bf16x8 __attribute__((ext_vector_type(8)));
typedef float f32x4 __attribute__((ext_vector_type(4)));

constexpr int NP   = 256;   // n_patches
constexpr int DM   = 1024;  // d_model
constexpr int PRED = 720;
constexpr int P0   = 233;   // first contributing patch
constexpr int NPC  = 23;    // patches 233..255
constexpr int TMIN = 7504;  // total_len - PRED

// ---- W fp32 -> bf16 (once per launch, into d_ws) ----
__global__ __launch_bounds__(256) void wconv(const float* __restrict__ W,
                                             __bf16* __restrict__ Wb) {
    const int i = (blockIdx.x * 256 + threadIdx.x) * 4;   // 64 blocks cover 65536
    const float4 v = *(const float4*)(W + i);
    __bf16 o[4] = {(__bf16)v.x, (__bf16)v.y, (__bf16)v.z, (__bf16)v.w};
    *(short4*)(Wb + i) = *(short4*)o;
}

// One block per batch. 512 threads = 8 waves: wave = (kwin 0..3) x (mtile 0..1).
// z[32][64] = x[b, P0+0..31, :] @ W^T  (rows >=23 are clamped/ignored).
// LDS-reduce 4 K-windows, then fold+bias+scale -> out[b][0:720]. No atomics.
__global__ __launch_bounds__(512, 4) void ph_fused(
    const float*  __restrict__ x,     // [512][256][1024]
    const __bf16* __restrict__ Wb,    // [64][1024] bf16 (ws)
    const float*  __restrict__ bias,  // [64]
    float* __restrict__ out)          // [512][720]
{
    const int b    = blockIdx.x;
    const int lane = threadIdx.x & 63;
    const int wave = threadIdx.x >> 6;       // 0..7
    const int m    = wave & 1;               // M-tile (patches m*16..m*16+15)
    const int kw   = wave >> 1;              // K-window 0..3 (256 each)
    const int r16  = lane & 15;
    const int kgrp = lane >> 4;

    __shared__ float red[4][32][68];         // 34.8 KB

    // A source row: patch P0 + m*16 + r16, clamped to 255 (rows 23..31 unused)
    const int p    = P0 + m * 16 + r16;
    const int peff = p > 255 ? 255 : p;
    const float* xrow = x + ((size_t)b * NP + peff) * DM;

    const int kbase = kw * 256;

    f32x4 acc[4];
    #pragma unroll
    for (int n = 0; n < 4; ++n) acc[n] = (f32x4){0.f, 0.f, 0.f, 0.f};

    #pragma unroll
    for (int s = 0; s < 8; ++s) {
        const int kk = kbase + s * 32 + kgrp * 8;

        const float4 a0 = *(const float4*)(xrow + kk);
        const float4 a1 = *(const float4*)(xrow + kk + 4);
        bf16x8 af;
        af[0]=(__bf16)a0.x; af[1]=(__bf16)a0.y; af[2]=(__bf16)a0.z; af[3]=(__bf16)a0.w;
        af[4]=(__bf16)a1.x; af[5]=(__bf16)a1.y; af[6]=(__bf16)a1.z; af[7]=(__bf16)a1.w;

        #pragma unroll
        for (int n = 0; n < 4; ++n) {
            const bf16x8 bf = *(const bf16x8*)(Wb + (size_t)(n * 16 + r16) * DM + kk);
            acc[n] = __builtin_amdgcn_mfma_f32_16x16x32_bf16(af, bf, acc[n], 0, 0, 0);
        }
    }

    // D layout (m89): row(patch-in-tile) = kgrp*4 + reg, col(j) = n*16 + r16.
    #pragma unroll
    for (int n = 0; n < 4; ++n)
        #pragma unroll
        for (int r = 0; r < 4; ++r)
            red[kw][m * 16 + kgrp * 4 + r][n * 16 + r16] = acc[n][r];

    __syncthreads();

    // Reduce 4 K-window partials: thread -> (row, 4 consecutive j).
    const int rr = threadIdx.x >> 4;          // 0..31
    const int j0 = (threadIdx.x & 15) * 4;    // 0..60
    f32x4 zsum;
    #pragma unroll
    for (int q = 0; q < 4; ++q) {
        float s = 0.f;
        #pragma unroll
        for (int w = 0; w < 4; ++w) s += red[w][rr][j0 + q];
        zsum[q] = s;
    }
    __syncthreads();
    #pragma unroll
    for (int q = 0; q < 4; ++q) red[0][rr][j0 + q] = zsum[q];
    __syncthreads();

    // Fold: out[b][o], o = 0..719. t = o + TMIN; patch hi = t>>5 (j = t&31),
    // patch lo = hi-1 (j+32). count 2 if hi <= 255 else 1.
    for (int o = threadIdx.x; o < PRED; o += 512) {
        const int t  = o + TMIN;
        const int ph = t >> 5;                // 234..256
        const int j  = t & 31;
        float v = red[0][ph - 1 - P0][j + 32] + bias[j + 32];
        if (ph <= 255) {
            v = (v + red[0][ph - P0][j] + bias[j]) * 0.5f;
        }
        out[(size_t)b * PRED + o] = v;
    }
}

extern "C" void kernel_launch(void* const* d_in, const int* in_sizes, int n_in,
                              void* d_out, int out_size, void* d_ws, size_t ws_size,
                              hipStream_t stream) {
    const float* x    = (const float*)d_in[0];
    const float* W    = (const float*)d_in[1];
    const float* bias = (const float*)d_in[2];
    float*  out = (float*)d_out;
    __bf16* Wb  = (__bf16*)d_ws;   // 128 KB

    wconv<<<64, 256, 0, stream>>>(W, Wb);
    ph_fused<<<dim3(512), dim3(512), 0, stream>>>(x, Wb, bias, out);
}

// Round 6
// 30.933 us; speedup vs baseline: 1.1663x; 1.0280x over previous
//
#include <hip/hip_runtime.h>
#include <stdint.h>

typedef __bf16 bf16x8 __attribute__((ext_vector_type(8)));
typedef float f32x4 __attribute__((ext_vector_type(4)));

constexpr int NP   = 256;   // n_patches
constexpr int DM   = 1024;  // d_model
constexpr int PRED = 720;
constexpr int P0   = 233;   // first contributing patch
constexpr int NPC  = 23;    // patches 233..255
constexpr int TMIN = 7504;  // total_len - PRED

// ---- W fp32 -> bf16 (once per launch, into d_ws) ----
__global__ __launch_bounds__(256) void wconv(const float* __restrict__ W,
                                             __bf16* __restrict__ Wb) {
    const int i = (blockIdx.x * 256 + threadIdx.x) * 4;
    const float4 v = *(const float4*)(W + i);
    __bf16 o[4] = {(__bf16)v.x, (__bf16)v.y, (__bf16)v.z, (__bf16)v.w};
    *(short4*)(Wb + i) = *(short4*)o;
}

// One block per batch; 512 thr = 8 waves = (ks 0..3) x (m 0..1).
// K processed in 4 quarters of 256, double-buffered in LDS:
//   Abuf[2][23 rows][1024 B]  (one quarter-row = 1 KB, XOR-swizzled) = 47104 B
// Stage: one global_load_lds_dwordx4 per row-quarter (contiguous 1 KB/wave-instr).
// Swizzle (both sides, rule 21): byte ^= (row&7)<<4.
// After the K-loop the same LDS is reused as red[4][32][68] for the reduce.
__global__ __launch_bounds__(512) void ph_fused(
    const float*  __restrict__ x,     // [512][256][1024]
    const __bf16* __restrict__ Wb,    // [64][1024] bf16 (ws)
    const float*  __restrict__ bias,  // [64]
    float* __restrict__ out)          // [512][720]
{
    __shared__ __align__(16) char smem[47104];

    const int b    = blockIdx.x;
    const int tid  = threadIdx.x;
    const int lane = tid & 63;
    const int wave = tid >> 6;        // 0..7
    const int r16  = lane & 15;
    const int kgrp = lane >> 4;
    const int m    = wave & 1;        // M-tile (16 patches)
    const int ks   = wave >> 1;       // K-sub window (64 per quarter)

    int row = m * 16 + r16;           // patch index in 0..31; clamp pad rows
    if (row > 22) row = 22;
    const int swzr = (row & 7) << 4;

    f32x4 acc[4];
    #pragma unroll
    for (int n = 0; n < 4; ++n) acc[n] = (f32x4){0.f, 0.f, 0.f, 0.f};

    const char* xbase = (const char*)(x + ((size_t)b * NP + P0) * DM);

    // stage quarter q into buffer `buf`: rows wave, wave+8, wave+16
    auto stage = [&](int q, int buf) {
        for (int r = wave; r < 23; r += 8) {
            const char* src = xbase + (size_t)r * 4096 + q * 1024
                            + ((lane * 16) ^ ((r & 7) << 4));   // pre-swizzled source
            char* dst = smem + buf * 23552 + r * 1024;          // linear dest
            __builtin_amdgcn_global_load_lds(
                (const __attribute__((address_space(1))) uint32_t*)src,
                (__attribute__((address_space(3))) uint32_t*)dst, 16, 0, 0);
        }
    };

    stage(0, 0);
    asm volatile("s_waitcnt vmcnt(0)" ::: "memory");
    __syncthreads();

    for (int q = 0; q < 4; ++q) {
        const int buf = q & 1;
        if (q < 3) stage(q + 1, buf ^ 1);      // prefetch next quarter (async)

        const char* arow = smem + buf * 23552 + row * 1024;
        #pragma unroll
        for (int st = 0; st < 2; ++st) {
            const int koff = ks * 256 + st * 128 + kgrp * 32;   // byte off in quarter
            const f32x4 a0 = *(const f32x4*)(arow + ((koff     ) ^ swzr));
            const f32x4 a1 = *(const f32x4*)(arow + ((koff + 16) ^ swzr));
            bf16x8 af;
            af[0]=(__bf16)a0[0]; af[1]=(__bf16)a0[1]; af[2]=(__bf16)a0[2]; af[3]=(__bf16)a0[3];
            af[4]=(__bf16)a1[0]; af[5]=(__bf16)a1[1]; af[6]=(__bf16)a1[2]; af[7]=(__bf16)a1[3];

            const int kkd = q * 256 + ks * 64 + st * 32 + kgrp * 8;  // elem k for B
            #pragma unroll
            for (int n = 0; n < 4; ++n) {
                const bf16x8 bf = *(const bf16x8*)(Wb + (size_t)(n * 16 + r16) * DM + kkd);
                acc[n] = __builtin_amdgcn_mfma_f32_16x16x32_bf16(af, bf, acc[n], 0, 0, 0);
            }
        }
        asm volatile("s_waitcnt vmcnt(0)" ::: "memory");
        __syncthreads();
    }

    // ---- reduce 4 K-subs + fold (alias smem as red[4][32][68]) ----
    float (*red)[32][68] = (float (*)[32][68])smem;

    // D layout (m89): row(patch) = kgrp*4 + reg (+m*16), col(j) = n*16 + r16.
    #pragma unroll
    for (int n = 0; n < 4; ++n)
        #pragma unroll
        for (int r = 0; r < 4; ++r)
            red[ks][m * 16 + kgrp * 4 + r][n * 16 + r16] = acc[n][r];

    __syncthreads();

    const int rr = tid >> 4;            // 0..31
    const int j0 = (tid & 15) * 4;      // 0..60
    f32x4 zs;
    #pragma unroll
    for (int qq = 0; qq < 4; ++qq) {
        float s = 0.f;
        #pragma unroll
        for (int w = 0; w < 4; ++w) s += red[w][rr][j0 + qq];
        zs[qq] = s;
    }
    __syncthreads();
    #pragma unroll
    for (int qq = 0; qq < 4; ++qq) red[0][rr][j0 + qq] = zs[qq];
    __syncthreads();

    // fold: t = o + TMIN; hi patch = t>>5 (j = t&31), lo patch = hi-1 (j+32)
    for (int o = tid; o < PRED; o += 512) {
        const int t  = o + TMIN;
        const int ph = t >> 5;          // 234..256
        const int j  = t & 31;
        float v = red[0][ph - 1 - P0][j + 32] + bias[j + 32];
        if (ph <= 255) v = (v + red[0][ph - P0][j] + bias[j]) * 0.5f;
        out[(size_t)b * PRED + o] = v;
    }
}

extern "C" void kernel_launch(void* const* d_in, const int* in_sizes, int n_in,
                              void* d_out, int out_size, void* d_ws, size_t ws_size,
                              hipStream_t stream) {
    const float* x    = (const float*)d_in[0];
    const float* W    = (const float*)d_in[1];
    const float* bias = (const float*)d_in[2];
    float*  out = (float*)d_out;
    __bf16* Wb  = (__bf16*)d_ws;   // 128 KB

    wconv<<<64, 256, 0, stream>>>(W, Wb);
    ph_fused<<<dim3(512), dim3(512), 0, stream>>>(x, Wb, bias, out);
}